// Round 6
// baseline (4663.029 us; speedup 1.0000x reference)
//
#include <hip/hip_runtime.h>
#include <math.h>

// RipsLayer: dim-0 persistence of Rips filtration on 4096 points in R^64.
// Phase 1: dense distance matrix D (64 MiB, in d_ws), diagonal = -INF.
// Phase 2: exact Prim replay, 1 workgroup / 4 waves:
//   - diag=-INF makes plain fmin fold auto-pin the newly added vertex
//     (min(-INF,r)=-INF is sticky; row_j's own diagonal pins col j)
//   - argmin runs over |mv|: tree cols (-INF) become +INF via free abs
//     input modifiers -> no masking pass, no mask bitfield
//   - single fused reduce per step (local tree -> value DPP -> ballot ->
//     u64 LDS combine), one no-drain barrier
//   - runner-up (2nd-best wave winner) speculative row prefetch in regs,
//     issued a full step early, surviving the no-drain barrier

#define N 4096
#define DF 64
#define INF __builtin_huge_valf()

// ---------------------------------------------------------------------------
// Phase 1: D[i][j] = sqrt(max(|x_i - x_j|^2, 1e-12)), diag = -INF (internal).
// ---------------------------------------------------------------------------
__global__ __launch_bounds__(256) void build_d_kernel(const float* __restrict__ x,
                                                      float* __restrict__ D) {
    __shared__ float As[64][68];
    __shared__ float Bs[64][68];
    const int bi = blockIdx.y * 64;
    const int bj = blockIdx.x * 64;
    const int t = threadIdx.x;

#pragma unroll
    for (int g = 0; g < 4; ++g) {
        int idx = t + 256 * g;
        int row = idx >> 4;
        int k4 = (idx & 15) << 2;
        float4 va = *(const float4*)(x + (size_t)(bi + row) * DF + k4);
        float4 vb = *(const float4*)(x + (size_t)(bj + row) * DF + k4);
        *(float4*)(&As[row][k4]) = va;
        *(float4*)(&Bs[row][k4]) = vb;
    }
    __syncthreads();

    const int ti = (t >> 4) << 2;
    const int tj = (t & 15) << 2;

    float acc[4][4];
#pragma unroll
    for (int r = 0; r < 4; ++r)
#pragma unroll
        for (int c = 0; c < 4; ++c) acc[r][c] = 0.0f;

    for (int k = 0; k < 64; k += 4) {
        float4 a[4], b[4];
#pragma unroll
        for (int r = 0; r < 4; ++r) a[r] = *(const float4*)(&As[ti + r][k]);
#pragma unroll
        for (int c = 0; c < 4; ++c) b[c] = *(const float4*)(&Bs[tj + c][k]);
#pragma unroll
        for (int r = 0; r < 4; ++r)
#pragma unroll
            for (int c = 0; c < 4; ++c) {
                float d0 = a[r].x - b[c].x;
                float d1 = a[r].y - b[c].y;
                float d2 = a[r].z - b[c].z;
                float d3 = a[r].w - b[c].w;
                float s = acc[r][c];
                s = fmaf(d0, d0, s);
                s = fmaf(d1, d1, s);
                s = fmaf(d2, d2, s);
                s = fmaf(d3, d3, s);
                acc[r][c] = s;
            }
    }

#pragma unroll
    for (int r = 0; r < 4; ++r) {
        int i = bi + ti + r;
        float4 v;
        float* vp = &v.x;
#pragma unroll
        for (int c = 0; c < 4; ++c) {
            int j = bj + tj + c;
            vp[c] = (i == j) ? -INF : sqrtf(fmaxf(acc[r][c], 1e-12f));
        }
        *(float4*)(D + (size_t)i * N + (bj + tj)) = v;
    }
}

// ---------------------------------------------------------------------------
// Barrier publishing LDS (lgkmcnt) but leaving global loads in flight.
// ---------------------------------------------------------------------------
__device__ __forceinline__ void barrier_no_drain() {
    __asm__ __volatile__("s_waitcnt lgkmcnt(0)\n\ts_barrier" ::: "memory");
}

#define DPP_MIN_STEP(x, ctrl)                                                  \
    x = fminf(x, __int_as_float(__builtin_amdgcn_update_dpp(                   \
                     0x7f800000, __float_as_int(x), ctrl, 0xF, 0xF, false)))

__device__ __forceinline__ float wave_min_f32_l63(float x) {
    DPP_MIN_STEP(x, 0x111);  // row_shr:1
    DPP_MIN_STEP(x, 0x112);  // row_shr:2
    DPP_MIN_STEP(x, 0x114);  // row_shr:4
    DPP_MIN_STEP(x, 0x118);  // row_shr:8
    DPP_MIN_STEP(x, 0x142);  // row_bcast:15
    DPP_MIN_STEP(x, 0x143);  // row_bcast:31
    return x;  // lane 63 holds the wave min
}

// ---------------------------------------------------------------------------
// Phase 2. Thread t owns cols [16t, 16t+16). Invariant: mv[i] == -INF iff
// col 16t+i is in the tree; argmin runs on |mv| (abs modifiers are free).
// ---------------------------------------------------------------------------
__global__ __launch_bounds__(256) void prim_kernel(const float* __restrict__ D,
                                                   float* __restrict__ out) {
    __shared__ __align__(16) unsigned long long part[2][4];
    const int t = threadIdx.x;
    const int lane = t & 63;
    const int wv = t >> 6;

    float mv[16];  // mind; -INF at tree cols (diag trick auto-pins)
    {
        const float4* rp0 = (const float4*)(D + 16 * t);  // row 0, D[0][0]=-INF
#pragma unroll
        for (int q = 0; q < 4; ++q) {
            float4 a = rp0[q];
            mv[4 * q + 0] = a.x; mv[4 * q + 1] = a.y;
            mv[4 * q + 2] = a.z; mv[4 * q + 3] = a.w;
        }
    }

    float sv[16];     // speculative row (runner-up), loaded a step ahead
    int specc = -1;   // which row sv holds

#pragma unroll 1
    for (int s = 1; s < N; ++s) {
        // ---- local argmin over |mv|, lowest index on ties ----
        float v[8];
        int id[8];
#pragma unroll
        for (int p = 0; p < 8; ++p) {
            float a = mv[2 * p], b = mv[2 * p + 1];
            bool c = fabsf(b) < fabsf(a);            // abs folds to modifier
            v[p] = fminf(fabsf(a), fabsf(b));
            id[p] = 2 * p + (c ? 1 : 0);
        }
#pragma unroll
        for (int st = 1; st < 8; st <<= 1)
#pragma unroll
            for (int i = 0; i < 8; i += 2 * st)
                if (v[i + st] < v[i]) {              // strict: keep lower idx
                    v[i] = v[i + st];
                    id[i] = id[i + st];
                }
        float lv = v[0];
        int lcol = (t << 4) | id[0];

        // ---- wave min (value DPP) + ballot index recovery ----
        float red = wave_min_f32_l63(lv);
        float wm = __int_as_float(
            __builtin_amdgcn_readlane(__float_as_int(red), 63));
        unsigned long long tied = __ballot(lv == wm);
        int src = __ffsll(tied) - 1;   // lowest lane == lowest col (blocked)
        int wcol = __builtin_amdgcn_readlane(lcol, src);
        unsigned long long wkey =
            ((unsigned long long)__float_as_uint(wm) << 32) | (unsigned)wcol;

        // ---- cross-wave combine: one no-drain barrier ----
        const int pb = s & 1;
        if (lane == 0) part[pb][wv] = wkey;
        barrier_no_drain();
        const ulonglong2* pp = (const ulonglong2*)&part[pb][0];
        ulonglong2 ab = pp[0], cd = pp[1];
        unsigned long long m01 = ab.x < ab.y ? ab.x : ab.y;
        unsigned long long M01 = ab.x < ab.y ? ab.y : ab.x;
        unsigned long long m23 = cd.x < cd.y ? cd.x : cd.y;
        unsigned long long M23 = cd.x < cd.y ? cd.y : cd.x;
        unsigned long long best = m01 < m23 ? m01 : m23;
        unsigned long long mxw = m01 < m23 ? M01 : M23;
        unsigned long long mnl = m01 < m23 ? m23 : m01;
        unsigned long long sec = mxw < mnl ? mxw : mnl;  // 2nd-best wave winner

        int j = __builtin_amdgcn_readfirstlane((int)(best & 0xffffffffULL));
        int dbits = __builtin_amdgcn_readfirstlane((int)(best >> 32));
        int sc = __builtin_amdgcn_readfirstlane((int)(sec & 0xffffffffULL));

        if (t == 0)
            *(float2*)(out + 2 * (s - 1)) =
                make_float2(0.0f, __uint_as_float((unsigned)dbits));

        if (s < N - 1) {
            if (j == specc) {
                // spec hit: row already resident/in-flight since last step.
                // Issue next speculation first, then fold from sv.
                float hold[16];
#pragma unroll
                for (int i = 0; i < 16; ++i) hold[i] = sv[i];
                const float4* sp = (const float4*)(D + (size_t)(unsigned)sc * N + 16 * t);
#pragma unroll
                for (int q = 0; q < 4; ++q) {
                    float4 a = sp[q];
                    sv[4 * q + 0] = a.x; sv[4 * q + 1] = a.y;
                    sv[4 * q + 2] = a.z; sv[4 * q + 3] = a.w;
                }
#pragma unroll
                for (int i = 0; i < 16; ++i) mv[i] = fminf(mv[i], hold[i]);
            } else {
                // miss: fetch row j; also re-speculate with sc
                const float4* rp = (const float4*)(D + (size_t)(unsigned)j * N + 16 * t);
                float4 r0 = rp[0], r1 = rp[1], r2 = rp[2], r3 = rp[3];
                const float4* sp = (const float4*)(D + (size_t)(unsigned)sc * N + 16 * t);
#pragma unroll
                for (int q = 0; q < 4; ++q) {
                    float4 a = sp[q];
                    sv[4 * q + 0] = a.x; sv[4 * q + 1] = a.y;
                    sv[4 * q + 2] = a.z; sv[4 * q + 3] = a.w;
                }
                mv[0] = fminf(mv[0], r0.x);   mv[1] = fminf(mv[1], r0.y);
                mv[2] = fminf(mv[2], r0.z);   mv[3] = fminf(mv[3], r0.w);
                mv[4] = fminf(mv[4], r1.x);   mv[5] = fminf(mv[5], r1.y);
                mv[6] = fminf(mv[6], r1.z);   mv[7] = fminf(mv[7], r1.w);
                mv[8] = fminf(mv[8], r2.x);   mv[9] = fminf(mv[9], r2.y);
                mv[10] = fminf(mv[10], r2.z); mv[11] = fminf(mv[11], r2.w);
                mv[12] = fminf(mv[12], r3.x); mv[13] = fminf(mv[13], r3.y);
                mv[14] = fminf(mv[14], r3.z); mv[15] = fminf(mv[15], r3.w);
            }
            specc = sc;
        }
    }
}

// ---------------------------------------------------------------------------
extern "C" void kernel_launch(void* const* d_in, const int* in_sizes, int n_in,
                              void* d_out, int out_size, void* d_ws, size_t ws_size,
                              hipStream_t stream) {
    const float* x = (const float*)d_in[0];
    float* D = (float*)d_ws;     // requires ws_size >= N*N*4 = 64 MiB
    float* out = (float*)d_out;  // [N-1][2]: (birth=0, death)

    dim3 grid(N / 64, N / 64);
    build_d_kernel<<<grid, 256, 0, stream>>>(x, D);
    prim_kernel<<<1, 256, 0, stream>>>(D, out);
}

// Round 7
// 4481.422 us; speedup vs baseline: 1.0405x; 1.0405x over previous
//
#include <hip/hip_runtime.h>
#include <math.h>

// RipsLayer: dim-0 persistence of Rips filtration on 4096 points in R^64.
// Phase 1: dense distance matrix D (64 MiB, in d_ws), diagonal = -INF.
// Phase 2: exact Prim replay, 1 workgroup x 1024 threads (16 waves, 4/SIMD):
//   - thread owns 4 cols -> tiny local chains, single-float4 row loads
//   - two-phase m1/m2 argmin (m1 over mind hides the in-flight row load)
//   - diag=-INF sticky fold + abs-modifier masking (no mask bitfield)
//   - cross-wave combine via ds_min_u64 on a triple-buffered LDS slot,
//     one no-drain barrier per step (global loads stay in flight)

#define N 4096
#define DF 64
#define INF __builtin_huge_valf()
#define NINFBITS 0xff800000u

// ---------------------------------------------------------------------------
// Phase 1: D[i][j] = sqrt(max(|x_i - x_j|^2, 1e-12)), diag = -INF (internal).
// ---------------------------------------------------------------------------
__global__ __launch_bounds__(256) void build_d_kernel(const float* __restrict__ x,
                                                      float* __restrict__ D) {
    __shared__ float As[64][68];
    __shared__ float Bs[64][68];
    const int bi = blockIdx.y * 64;
    const int bj = blockIdx.x * 64;
    const int t = threadIdx.x;

#pragma unroll
    for (int g = 0; g < 4; ++g) {
        int idx = t + 256 * g;
        int row = idx >> 4;
        int k4 = (idx & 15) << 2;
        float4 va = *(const float4*)(x + (size_t)(bi + row) * DF + k4);
        float4 vb = *(const float4*)(x + (size_t)(bj + row) * DF + k4);
        *(float4*)(&As[row][k4]) = va;
        *(float4*)(&Bs[row][k4]) = vb;
    }
    __syncthreads();

    const int ti = (t >> 4) << 2;
    const int tj = (t & 15) << 2;

    float acc[4][4];
#pragma unroll
    for (int r = 0; r < 4; ++r)
#pragma unroll
        for (int c = 0; c < 4; ++c) acc[r][c] = 0.0f;

    for (int k = 0; k < 64; k += 4) {
        float4 a[4], b[4];
#pragma unroll
        for (int r = 0; r < 4; ++r) a[r] = *(const float4*)(&As[ti + r][k]);
#pragma unroll
        for (int c = 0; c < 4; ++c) b[c] = *(const float4*)(&Bs[tj + c][k]);
#pragma unroll
        for (int r = 0; r < 4; ++r)
#pragma unroll
            for (int c = 0; c < 4; ++c) {
                float d0 = a[r].x - b[c].x;
                float d1 = a[r].y - b[c].y;
                float d2 = a[r].z - b[c].z;
                float d3 = a[r].w - b[c].w;
                float s = acc[r][c];
                s = fmaf(d0, d0, s);
                s = fmaf(d1, d1, s);
                s = fmaf(d2, d2, s);
                s = fmaf(d3, d3, s);
                acc[r][c] = s;
            }
    }

#pragma unroll
    for (int r = 0; r < 4; ++r) {
        int i = bi + ti + r;
        float4 v;
        float* vp = &v.x;
#pragma unroll
        for (int c = 0; c < 4; ++c) {
            int j = bj + tj + c;
            vp[c] = (i == j) ? -INF : sqrtf(fmaxf(acc[r][c], 1e-12f));
        }
        *(float4*)(D + (size_t)i * N + (bj + tj)) = v;
    }
}

// ---------------------------------------------------------------------------
// Barrier publishing LDS (lgkmcnt) but leaving global loads in flight.
// ---------------------------------------------------------------------------
__device__ __forceinline__ void barrier_no_drain() {
    __asm__ __volatile__("s_waitcnt lgkmcnt(0)\n\ts_barrier" ::: "memory");
}

#define DPP_MIN_STEP(x, ctrl)                                                  \
    x = fminf(x, __int_as_float(__builtin_amdgcn_update_dpp(                   \
                     0x7f800000, __float_as_int(x), ctrl, 0xF, 0xF, false)))

// Wave64 min in lane 63, then broadcast + ballot index recovery.
// Blocked col ownership -> lowest tied lane holds lowest col (exact ties).
__device__ __forceinline__ unsigned long long wave_argmin_key(float lv, int lcol) {
    float x = lv;
    DPP_MIN_STEP(x, 0x111);  // row_shr:1
    DPP_MIN_STEP(x, 0x112);  // row_shr:2
    DPP_MIN_STEP(x, 0x114);  // row_shr:4
    DPP_MIN_STEP(x, 0x118);  // row_shr:8
    DPP_MIN_STEP(x, 0x142);  // row_bcast:15
    DPP_MIN_STEP(x, 0x143);  // row_bcast:31
    float wm = __int_as_float(__builtin_amdgcn_readlane(__float_as_int(x), 63));
    unsigned long long tied = __ballot(lv == wm);
    int src = __ffsll(tied) - 1;
    int wcol = __builtin_amdgcn_readlane(lcol, src);
    return ((unsigned long long)__float_as_uint(wm) << 32) | (unsigned)wcol;
}

// Local argmin over 4 values, strict '<' keeps the lowest index on ties.
__device__ __forceinline__ void argmin4(const float* __restrict__ m,
                                        float& lv, int& li) {
    bool c01 = m[1] < m[0];
    float v01 = fminf(m[0], m[1]);
    int i01 = c01 ? 1 : 0;
    bool c23 = m[3] < m[2];
    float v23 = fminf(m[2], m[3]);
    int i23 = c23 ? 3 : 2;
    bool cf = v23 < v01;
    lv = cf ? v23 : v01;
    li = cf ? i23 : i01;
}

// ---------------------------------------------------------------------------
// Phase 2. Thread t owns cols [4t, 4t+4). Invariant: mv[i] == -INF iff col
// 4t+i is in the tree (pinned at select; diag=-INF keeps fmin folds sticky).
// ---------------------------------------------------------------------------
__global__ __launch_bounds__(1024) void prim_kernel(const float* __restrict__ D,
                                                    float* __restrict__ out) {
    __shared__ unsigned long long slot[3];  // triple-buffered argmin accumulator
    const int t = threadIdx.x;
    const int lane = t & 63;

    if (t == 0) { slot[0] = ~0ULL; slot[1] = ~0ULL; slot[2] = ~0ULL; }
    __syncthreads();

    float mv[4];  // mind; -INF at tree cols
    float rv[4];  // row of last-selected vertex (in flight across backedge)
    {
        float4 a = *(const float4*)(D + 4 * t);  // row 0; D[0][0] = -INF
        mv[0] = a.x; mv[1] = a.y; mv[2] = a.z; mv[3] = a.w;
        rv[0] = a.x; rv[1] = a.y; rv[2] = a.z; rv[3] = a.w;
    }

#pragma unroll 1
    for (int s = 1; s < N; ++s) {
        // ---- m1: argmin over |mv| (abs folds to input modifiers; tree
        //      cols -INF -> +INF). No dependence on the in-flight row. ----
        float am[4] = {fabsf(mv[0]), fabsf(mv[1]), fabsf(mv[2]), fabsf(mv[3])};
        float lv1; int li1;
        argmin4(am, lv1, li1);
        unsigned long long key1 = wave_argmin_key(lv1, 4 * t + li1);

        // ---- m2: argmin over arrived row, tree cols masked to INF ----
        float mr[4];
#pragma unroll
        for (int i = 0; i < 4; ++i)
            mr[i] = (__float_as_uint(mv[i]) == NINFBITS) ? INF : rv[i];
        float lv2; int li2;
        argmin4(mr, lv2, li2);
        unsigned long long key2 = wave_argmin_key(lv2, 4 * t + li2);

        // ---- publish: one ds_min_u64 per wave; reset slot 2 steps ahead ----
        unsigned long long kw = key1 < key2 ? key1 : key2;
        if (lane == 0) atomicMin(&slot[s % 3], kw);
        if (t == 0) slot[(s + 1) % 3] = ~0ULL;  // used at s+1... reset target
                                                // is only re-read at s+1 after
                                                // barrier(s); writers at s+1
                                                // come after barrier(s) too
        // ---- fold row into mind (fmin is sticky at -INF tree cols) ----
#pragma unroll
        for (int i = 0; i < 4; ++i) mv[i] = fminf(mv[i], rv[i]);

        barrier_no_drain();

        unsigned long long best = slot[s % 3];
        int j = __builtin_amdgcn_readfirstlane((int)(best & 0xffffffffULL));
        int dbits = __builtin_amdgcn_readfirstlane((int)(best >> 32));

        // ---- issue next row load immediately (consumed next iter in m2) ----
        float4 nr = *(const float4*)(D + (size_t)(unsigned)j * N + 4 * t);

        if (t == 0)
            *(float2*)(out + 2 * (s - 1)) =
                make_float2(0.0f, __uint_as_float((unsigned)dbits));

        // ---- pin newly-added col j in mv ----
        int base = 4 * t;
#pragma unroll
        for (int i = 0; i < 4; ++i)
            if (base + i == j) mv[i] = -INF;

        rv[0] = nr.x; rv[1] = nr.y; rv[2] = nr.z; rv[3] = nr.w;
    }
}

// ---------------------------------------------------------------------------
extern "C" void kernel_launch(void* const* d_in, const int* in_sizes, int n_in,
                              void* d_out, int out_size, void* d_ws, size_t ws_size,
                              hipStream_t stream) {
    const float* x = (const float*)d_in[0];
    float* D = (float*)d_ws;     // requires ws_size >= N*N*4 = 64 MiB
    float* out = (float*)d_out;  // [N-1][2]: (birth=0, death)

    dim3 grid(N / 64, N / 64);
    build_d_kernel<<<grid, 256, 0, stream>>>(x, D);
    prim_kernel<<<1, 1024, 0, stream>>>(D, out);
}